// Round 5
// baseline (210.926 us; speedup 1.0000x reference)
//
#include <hip/hip_runtime.h>
#include <hip/hip_bf16.h>

// Problem: B,W,H,L = 2,32,32,32 -> N=65536 voxels; D=512, E=64 heads, V=16.
// Round-16: R15's flat 8-deep staging (128 VGPRs of live load data) collides
// with the __launch_bounds__(256,4) cap of 128 total -> RA must spill load
// results to scratch; that's why the fence bought only ~10%, not 3x. Fix:
// rolling 2-buffer pipeline at QSTEP=4 k-steps/stage (64 VGPRs of load data,
// ~110 raw total) -> no spill, 8 loads/wave permanently in flight, AND the
// full 16 waves/CU occupancy (1024 blocks all resident). Prologue also
// overlaps W-tile and btg load latencies (issue both, then convert/stage).
#define DDIM 512
#define VDIM 16
#define EHEADS 64
#define NVOX 65536
#define QPERH 16
#define SLICE (NVOX / QPERH)          // 4096 voxels per block slice
#define NBLOCKS (EHEADS * QPERH)      // 1024 blocks = 4/CU, all resident
#define WRANGE (SLICE / 4)            // 1024 voxels per wave
#define WCAP 256                      // per-wave list cap (mean ~16, >25 sigma)
#define KSTEPS 16                     // K=32 MFMA steps
#define QSTEP 4                       // k-steps per pipeline stage (32 VGPRs)

typedef __bf16  bf16x8  __attribute__((ext_vector_type(8)));
typedef float   floatx4 __attribute__((ext_vector_type(4)));

// Issue QSTEP k-steps of A-fragment loads (8 dwordx4) into a register buffer.
#define ISSUE_Q(LO, HI, Q)                                                  \
    _Pragma("unroll")                                                       \
    for (int k = 0; k < QSTEP; ++k) {                                       \
        const float* p = rowp + ((Q) * QSTEP + k) * 32;                     \
        LO[k] = *(const floatx4*)p;                                         \
        HI[k] = *(const floatx4*)(p + 4);                                   \
    }

// Convert + MFMA QSTEP k-steps from a register buffer.
#define COMPUTE_Q(LO, HI, Q)                                                \
    _Pragma("unroll")                                                       \
    for (int k = 0; k < QSTEP; ++k) {                                       \
        bf16x8 af;                                                          \
        _Pragma("unroll")                                                   \
        for (int j = 0; j < 4; ++j) {                                       \
            af[j]     = (__bf16)LO[k][j];                                   \
            af[4 + j] = (__bf16)HI[k][j];                                   \
        }                                                                   \
        acc = __builtin_amdgcn_mfma_f32_16x16x32_bf16(                      \
                  af, Wfrag[((Q) * QSTEP + k) * 64 + lane], acc, 0, 0, 0);  \
    }

__global__ __launch_bounds__(256, 4) void fused_decode_kernel(
    const int*   __restrict__ btg,   // (NVOX,)
    const int*   __restrict__ b2h,   // (256,)
    const float* __restrict__ x,     // (NVOX, D)
    const float* __restrict__ Wh,    // (E, V, D)
    const float* __restrict__ bh,    // (E, V)
    float*       __restrict__ out)   // (NVOX, V)
{
    __shared__ int    lut[256];                   // 1 KB
    __shared__ bf16x8 Wfrag[KSTEPS * 64];         // 16 KB, MFMA fragment order
    __shared__ int    wlist[4][WCAP];             // 4 KB, per-wave lists

    const int tid  = threadIdx.x;
    const int lane = tid & 63;
    const int wv   = tid >> 6;                    // wave in block (0..3)
    const int e    = blockIdx.x >> 4;             // head
    const int q    = blockIdx.x & (QPERH - 1);    // slice
    const int m    = lane & 15;
    const int quad = lane >> 4;

    lut[tid] = b2h[tid];

    // ---- Prologue: issue W-tile AND btg loads, then convert/stage ---------
    // Wfrag[k0*64 + ln] = W[e][ln&15][k0*32 + (ln>>4)*8 + j], j=0..7
    floatx4 w0[4], w1[4];
#pragma unroll
    for (int i = 0; i < 4; ++i) {
        const int f  = i * 256 + tid;
        const int k0 = f >> 6, ln = f & 63;
        const float* src = Wh + ((size_t)e * VDIM + (ln & 15)) * DDIM
                              + k0 * 32 + (ln >> 4) * 8;
        w0[i] = *(const floatx4*)src;
        w1[i] = *(const floatx4*)(src + 4);
    }
    const int wbase = q * SLICE + wv * WRANGE;
    int bt[WRANGE / 64];
#pragma unroll
    for (int i = 0; i < WRANGE / 64; ++i)         // 16 independent loads
        bt[i] = btg[wbase + i * 64 + lane];
    __builtin_amdgcn_sched_barrier(0);            // all 24 loads in flight

#pragma unroll
    for (int i = 0; i < 4; ++i) {                 // waits W only (vmcnt(16))
        bf16x8 bf;
#pragma unroll
        for (int j = 0; j < 4; ++j) {
            bf[j] = (__bf16)w0[i][j]; bf[4 + j] = (__bf16)w1[i][j];
        }
        Wfrag[i * 256 + tid] = bf;
    }
    __syncthreads();                              // ONLY barrier in the kernel

    // ---- Per-wave atomic-free scan: ballot prefix on preloaded bt[] -------
    int cnt = 0;
#pragma unroll
    for (int i = 0; i < WRANGE / 64; ++i) {
        const bool match = (lut[bt[i]] == e);
        const unsigned long long mk = __ballot(match);
        if (match) {
            const int p = cnt + __popcll(mk & ((1ull << lane) - 1ull));
            if (p < WCAP) wlist[wv][p] = wbase + i * 64 + lane;
        }
        cnt += __popcll(mk);
    }
    if (cnt > WCAP) cnt = WCAP;

    const float bv = bh[e * VDIM + m];
    const int ntiles = (cnt + 15) >> 4;

    // ---- Decode: rolling 2-buffer register pipeline, schedule pinned ------
    // A-fragment for lane l, kstep k: row (l&15), cols k*32 + (l>>4)*8 .. +8
    for (int t = 0; t < ntiles; ++t) {
        const int rs = t * 16;
        int rm = rs + m;
        if (rm >= cnt) rm = cnt - 1;              // clamp tail (stores guarded)
        const int idx_m = wlist[wv][rm];          // lane L holds row L&15
        const float* rowp = x + (size_t)idx_m * DDIM + (quad << 3);

        floatx4 acc = {0.f, 0.f, 0.f, 0.f};
        floatx4 alo[QSTEP], ahi[QSTEP], blo[QSTEP], bhi[QSTEP];

        ISSUE_Q(alo, ahi, 0)                      // Q0 -> A
        ISSUE_Q(blo, bhi, 1)                      // Q1 -> B
        __builtin_amdgcn_sched_barrier(0);
        COMPUTE_Q(alo, ahi, 0)                    // waits vmcnt(8)
        __builtin_amdgcn_sched_barrier(0);
        ISSUE_Q(alo, ahi, 2)                      // Q2 -> A
        __builtin_amdgcn_sched_barrier(0);
        COMPUTE_Q(blo, bhi, 1)                    // waits vmcnt(8)
        __builtin_amdgcn_sched_barrier(0);
        ISSUE_Q(blo, bhi, 3)                      // Q3 -> B
        __builtin_amdgcn_sched_barrier(0);
        COMPUTE_Q(alo, ahi, 2)                    // waits vmcnt(8)
        __builtin_amdgcn_sched_barrier(0);
        COMPUTE_Q(blo, bhi, 3)

        // D: col = m (output v), row = quad*4 + r (voxel within tile)
#pragma unroll
        for (int r = 0; r < 4; ++r) {
            const int o = rs + quad * 4 + r;
            if (o < cnt)
                out[(size_t)wlist[wv][o] * VDIM + m] = acc[r] + bv;
        }
    }
}

extern "C" void kernel_launch(void* const* d_in, const int* in_sizes, int n_in,
                              void* d_out, int out_size, void* d_ws, size_t ws_size,
                              hipStream_t stream)
{
    const int*   btg = (const int*)d_in[0];
    const float* x   = (const float*)d_in[1];
    const float* Wh  = (const float*)d_in[2];
    const float* bh  = (const float*)d_in[3];
    const int*   b2h = (const int*)d_in[4];
    float*       out = (float*)d_out;
    (void)d_ws; (void)ws_size; (void)in_sizes; (void)n_in; (void)out_size;

    fused_decode_kernel<<<NBLOCKS, 256, 0, stream>>>(btg, b2h, x, Wh, bh, out);
}